// Round 11
// baseline (342.408 us; speedup 1.0000x reference)
//
#include <hip/hip_runtime.h>

typedef float v4f __attribute__((ext_vector_type(4)));

namespace {
constexpr int B_     = 8;
constexpr int NT_    = 256;
constexpr int NX_    = 256;
constexpr int NREC_  = 64;
constexpr int PIECES = 16;             // 128 blocks (R13 geometry)
constexpr int IROWS  = 16;             // interior rows per strip
constexpr int G      = 16;             // steps per round
constexpr int ROUNDS = NT_ / G;        // 16 (15 handoffs)
constexpr int NB     = 12;             // 12 bands x 4 rows
constexpr int NTHR   = NB * 64;        // 768 threads
constexpr int NBLK   = B_ * PIECES;    // 128 blocks
constexpr float DT2  = 1e-6f;          // DT*DT
constexpr float KLAP = 1e-8f;          // DT*DT/(DH*DH)
constexpr size_t FLAGS_BYTES = 4096;
constexpr int RCAP = 6;
} // namespace

__device__ __forceinline__ float dpp_shr1(float v) {
    return __int_as_float(__builtin_amdgcn_update_dpp(
        0, __float_as_int(v), 0x138 /*WAVE_SHR1*/, 0xF, 0xF, true));
}
__device__ __forceinline__ float dpp_shl1(float v) {
    return __int_as_float(__builtin_amdgcn_update_dpp(
        0, __float_as_int(v), 0x130 /*WAVE_SHL1*/, 0xF, 0xF, true));
}

// R17 post-mortem: the ~130us residue is the round-boundary exchange
// SERIALIZATION (~8us x 15), not barrier count or step structure.
// R18: NO block-wide barriers in the main loop.
//  - Steps: R14's proven 3-slot prog[band] dataflow (poll band+-1 >= t, read
//    pub[t%3], compute, write pub[(t+1)%3], release t+1).
//  - Exchange dissolved into per-band handshakes: interior band publishes its
//    own slab after step 16, wave-local vmcnt drain, sets ITS flag; ghost band
//    polls its one source flag, refills, republishes slot (t0+16)%3, releases
//    prog=t0+16. Interior never stalls on the block; refill delay propagates
//    inward 1 band/step and hides under compute.
//  - Republish WAR guard: ghost waits prog[inner-nbr] >= t0+14 (interior's
//    last read of that slot is its step t0+13). All other stale/racy reads
//    land in the trapezoid dead cone -> absmax bit-identical.
//  - Receivers: owner thread stores to out directly (flush barrier gone).
__device__ __forceinline__ void store_v4_sys(float* p, v4f v) {
    asm volatile("global_store_dwordx4 %0, %1, off sc0 sc1"
                 :: "v"(p), "v"(v) : "memory");
}
__device__ __forceinline__ v4f load_v4_sys(const float* p) {
    v4f r;
    asm volatile("global_load_dwordx4 %0, %1, off sc0 sc1"
                 : "=v"(r) : "v"(p) : "memory");
    return r;
}

extern "C" __global__
__attribute__((amdgpu_flat_work_group_size(NTHR, NTHR), amdgpu_waves_per_eu(4, 4)))
void wave_reg_kernel(const float* __restrict__ x,
                     const float* __restrict__ vp,
                     const int* __restrict__ src_loc,
                     const int* __restrict__ rec_loc,
                     float* __restrict__ out,
                     int* __restrict__ flags,   // [128][4] per-band round flags
                     float* __restrict__ gbuf)  // [par2][128][lvl2][16][256]
{
    __shared__ float pub[3][2][NB][256];   // 73.7 KB [slot][top/bot][band][col]
    __shared__ int   prog[NB];             // per-band published level
    __shared__ float wav[NT_];             // 1 KB wavelet

    const int bid  = blockIdx.x;
    const int b    = bid & 7;
    const int p    = bid >> 3;             // 0..15
    const int blk  = b * PIECES + p;
    const int tid  = threadIdx.x;
    const int band = tid >> 6;             // wave id 0..11 -> 4 ext rows
    const int lane = tid & 63;
    const int c0   = lane << 2;            // first owned col (0..252)
    const int grt  = p * IROWS - G + (band << 2);  // global row of owned row 0

    // trapezoid cutoffs {3,7,11,15,16,16,16,16,15,11,7,3} (R13-proven)
    const int cut = (band < 4) ? ((band << 2) + 3)
                  : ((band < 8) ? G : (47 - (band << 2)));

    if (tid < NT_) wav[tid] = x[b * NT_ + tid];

    // cf = vp^2*KLAP masked; cf2 = 2 - 4*cf
    v4f cf[4], cf2[4];
#pragma unroll
    for (int i = 0; i < 4; ++i) {
        int gr = grt + i;
        int crow = gr < 0 ? 0 : (gr > 255 ? 255 : gr);
        bool rowok = (gr >= 1) && (gr <= 254);
        v4f vv = *(const v4f*)&vp[crow * NX_ + c0];
        float cc[4];
#pragma unroll
        for (int k = 0; k < 4; ++k) {
            int col = c0 + k;
            float vk = (k == 0) ? vv.x : (k == 1) ? vv.y : (k == 2) ? vv.z : vv.w;
            cc[k] = (rowok && col >= 1 && col <= 254) ? vk * vk * KLAP : 0.f;
        }
        cf[i].x = cc[0]; cf[i].y = cc[1]; cf[i].z = cc[2]; cf[i].w = cc[3];
        cf2[i].x = 2.f - 4.f * cc[0]; cf2[i].y = 2.f - 4.f * cc[1];
        cf2[i].z = 2.f - 4.f * cc[2]; cf2[i].w = 2.f - 4.f * cc[3];
    }

    // source ownership (ghost rows included: ghost evolution must replay it)
    const int sz = src_loc[b * 2 + 0], sx = src_loc[b * 2 + 1];
    const int si = sz - grt;
    const int sj = sx - c0;
    const bool has_src = ((unsigned)si < 4u) && ((unsigned)sj < 4u);
    const bool wave_has_src = __any(has_src);

    // receiver slots: interior owner only (unique writer). pk=(r<<4)|(i<<2)|j
    int rs[RCAP]; int rcnt = 0;
#pragma unroll 1
    for (int r = 0; r < NREC_; ++r) {
        int rz = rec_loc[(b * NREC_ + r) * 2 + 0];
        int rx = rec_loc[(b * NREC_ + r) * 2 + 1];
        int i = rz - grt, j = rx - c0;
        if (rz >= p * IROWS && rz < p * IROWS + IROWS &&
            (unsigned)i < 4u && (unsigned)j < 4u) {
            if (rcnt < RCAP) rs[rcnt] = (r << 4) | (i << 2) | j;
            ++rcnt;
        }
    }
    if (rcnt > RCAP) rcnt = RCAP;
    const bool wave_has_rec = __any(rcnt > 0);
    float* outb = out + (size_t)b * NT_ * NREC_;

    v4f A[4], Bv[4];
    {
        v4f z = {0.f, 0.f, 0.f, 0.f};
#pragma unroll
        for (int i = 0; i < 4; ++i) { A[i] = z; Bv[i] = z; }
    }

    // initial publish: level 0 into slot 0; prog = 0. Only barrier in kernel.
    *(v4f*)&pub[0][0][band][c0] = A[0];
    *(v4f*)&pub[0][1][band][c0] = A[3];
    if (lane == 0) prog[band] = 0;
    __syncthreads();

    auto gptr = [&](int e, int bk, int lvl, int rr) -> float* {
        return gbuf + ((((size_t)(e & 1) * NBLK + bk) * 2 + lvl) * 16 + rr) * 256;
    };

// one stencil row: literal index I only (rule #20)
#define ROW(I, NV, SV) do {                                                   \
    float wv = dpp_shr1(C[I].w);                                              \
    float ev = dpp_shl1(C[I].x);                                              \
    v4f hn;                                                                   \
    { float sm = ((NV).x + (SV).x) + (wv     + C[I].y);                       \
      hn.x = fmaf(cf[I].x, sm, fmaf(cf2[I].x, C[I].x, -P[I].x)); }            \
    { float sm = ((NV).y + (SV).y) + (C[I].x + C[I].z);                       \
      hn.y = fmaf(cf[I].y, sm, fmaf(cf2[I].y, C[I].y, -P[I].y)); }            \
    { float sm = ((NV).z + (SV).z) + (C[I].y + C[I].w);                       \
      hn.z = fmaf(cf[I].z, sm, fmaf(cf2[I].z, C[I].z, -P[I].z)); }            \
    { float sm = ((NV).w + (SV).w) + (C[I].z + ev);                           \
      hn.w = fmaf(cf[I].w, sm, fmaf(cf2[I].w, C[I].w, -P[I].w)); }            \
    P[I] = hn;                                                                \
} while (0)

    // one step: C = level t (pub slot t%3), computes t+1 into P, publishes
    // into slot (t+1)%3, releases prog = t+1. No block barrier.
    auto step = [&](v4f (&C)[4], v4f (&P)[4], int t) {
        const int s3  = t % 3;
        const int nxt = (s3 == 2) ? 0 : s3 + 1;
        if (band > 0)
            while (__hip_atomic_load(&prog[band - 1], __ATOMIC_ACQUIRE,
                                     __HIP_MEMORY_SCOPE_WORKGROUP) < t)
                __builtin_amdgcn_s_sleep(1);
        if (band < NB - 1)
            while (__hip_atomic_load(&prog[band + 1], __ATOMIC_ACQUIRE,
                                     __HIP_MEMORY_SCOPE_WORKGROUP) < t)
                __builtin_amdgcn_s_sleep(1);
        v4f nn, ss;
        if (band > 0)      nn = *(const v4f*)&pub[s3][1][band - 1][c0];
        else               { nn.x = 0.f; nn.y = 0.f; nn.z = 0.f; nn.w = 0.f; }
        if (band < NB - 1) ss = *(const v4f*)&pub[s3][0][band + 1][c0];
        else               { ss.x = 0.f; ss.y = 0.f; ss.z = 0.f; ss.w = 0.f; }
        ROW(1, C[0], C[2]);                // halo-free rows first
        ROW(2, C[1], C[3]);
        ROW(0, nn,   C[1]);
        ROW(3, C[2], ss);
        if (wave_has_src) {
            const float sv = DT2 * wav[t];
#pragma unroll
            for (int i = 0; i < 4; ++i) {
                if (has_src && si == i) {
                    if      (sj == 0) P[i].x += sv;
                    else if (sj == 1) P[i].y += sv;
                    else if (sj == 2) P[i].z += sv;
                    else              P[i].w += sv;
                }
            }
        }
        *(v4f*)&pub[nxt][0][band][c0] = P[0];
        *(v4f*)&pub[nxt][1][band][c0] = P[3];
        if (lane == 0)
            __hip_atomic_store(&prog[band], t + 1, __ATOMIC_RELEASE,
                               __HIP_MEMORY_SCOPE_WORKGROUP);
        if (wave_has_rec) {                // direct store, off critical path
#pragma unroll
            for (int kk = 0; kk < RCAP; ++kk) {
                if (rcnt > kk) {
                    int pk = rs[kk];
                    int i = (pk >> 2) & 3, j = pk & 3, r = pk >> 4;
                    v4f t01 = (i & 1) ? P[1] : P[0];
                    v4f t23 = (i & 1) ? P[3] : P[2];
                    v4f rw  = (i & 2) ? t23 : t01;
                    float c01 = (j & 1) ? rw.y : rw.x;
                    float c23 = (j & 1) ? rw.w : rw.z;
                    outb[t * NREC_ + r] = (j & 2) ? c23 : c01;
                }
            }
        }
    };

    int t0 = 0;
#pragma unroll 1
    for (int e = 0; e < ROUNDS; ++e, t0 += G) {
#pragma unroll 1
        for (int k = 1; k <= cut; k += 2) {
            step(A, Bv, t0 + k - 1);       // odd step:  Bv <- new level
            if (k < cut) step(Bv, A, t0 + k);  // even step: A <- new level
        }
        // ---- per-band round boundary (no block barrier) ----
        if (cut == G) {
            // interior/publisher band (4..7): A=t0+16, Bv=t0+15; prog=t0+16.
            if (e < ROUNDS - 1) {
                int rr0 = (band - 4) << 2;
#pragma unroll
                for (int i = 0; i < 4; ++i) {
                    store_v4_sys(&gptr(e, blk, 0, rr0 + i)[c0], A[i]);
                    store_v4_sys(&gptr(e, blk, 1, rr0 + i)[c0], Bv[i]);
                }
                asm volatile("s_waitcnt vmcnt(0)" ::: "memory"); // wave-local
                __hip_atomic_store(&flags[blk * 4 + (band - 4)], e + 1,
                                   __ATOMIC_RELAXED, __HIP_MEMORY_SCOPE_SYSTEM);
            }
        } else {
            // ghost band: let neighbors finish their round (needs >= t0+15)
            if (lane == 0)
                __hip_atomic_store(&prog[band], t0 + 15, __ATOMIC_RELEASE,
                                   __HIP_MEMORY_SCOPE_WORKGROUP);
            if (e < ROUNDS - 1) {
                const bool top    = band < 4;
                const int  srcblk = top ? blk - 1 : blk + 1;
                const bool have   = top ? (p > 0) : (p < PIECES - 1);
                if (have) {
                    const int fi = top ? band : band - 8;
                    if (lane == 0)
                        while (__hip_atomic_load(&flags[srcblk * 4 + fi],
                                 __ATOMIC_RELAXED,
                                 __HIP_MEMORY_SCOPE_SYSTEM) < e + 1)
                            __builtin_amdgcn_s_sleep(1);
                    const int rr0 = top ? (band << 2) : ((band - 8) << 2);
#pragma unroll
                    for (int i = 0; i < 4; ++i) {
                        A[i]  = load_v4_sys(&gptr(e, srcblk, 0, rr0 + i)[c0]);
                        Bv[i] = load_v4_sys(&gptr(e, srcblk, 1, rr0 + i)[c0]);
                    }
                    asm volatile("s_waitcnt vmcnt(0)" ::: "memory");
                    __builtin_amdgcn_sched_barrier(0);
                }
                // WAR guard: inner neighbor must have finished its step t0+13
                // reads of slot (t0+16)%3 before we republish it. For ghost
                // inner-neighbors the t0+15 jump satisfies this trivially.
                const int inn = top ? band + 1 : band - 1;
                while (__hip_atomic_load(&prog[inn], __ATOMIC_ACQUIRE,
                                         __HIP_MEMORY_SCOPE_WORKGROUP) < t0 + 14)
                    __builtin_amdgcn_s_sleep(1);
                const int s3n = (t0 + G) % 3;
                *(v4f*)&pub[s3n][0][band][c0] = A[0];
                *(v4f*)&pub[s3n][1][band][c0] = A[3];
                if (lane == 0)
                    __hip_atomic_store(&prog[band], t0 + G, __ATOMIC_RELEASE,
                                       __HIP_MEMORY_SCOPE_WORKGROUP);
            }
        }
    }
#undef ROW
}

extern "C" void kernel_launch(void* const* d_in, const int* in_sizes, int n_in,
                              void* d_out, int out_size, void* d_ws, size_t ws_size,
                              hipStream_t stream) {
    const float* x   = (const float*)d_in[0];
    const float* vp  = (const float*)d_in[1];
    const int*   src = (const int*)d_in[2];
    const int*   rec = (const int*)d_in[3];
    float*       o   = (float*)d_out;
    int*   flags = (int*)d_ws;
    float* gbuf  = (float*)((char*)d_ws + FLAGS_BYTES);
    (void)hipMemsetAsync(d_ws, 0, FLAGS_BYTES, stream);   // flags must start at 0
    hipLaunchKernelGGL(wave_reg_kernel, dim3(NBLK), dim3(NTHR), 0, stream,
                       x, vp, src, rec, o, flags, gbuf);
}

// Round 12
// 294.962 us; speedup vs baseline: 1.1609x; 1.1609x over previous
//
#include <hip/hip_runtime.h>

typedef float v4f __attribute__((ext_vector_type(4)));

namespace {
constexpr int B_     = 8;
constexpr int NT_    = 256;
constexpr int NX_    = 256;
constexpr int NREC_  = 64;
constexpr int PIECES = 16;             // 128 blocks (R13 champion geometry)
constexpr int IROWS  = 16;             // interior rows per strip
constexpr int G      = 16;             // ghost width = steps per round
constexpr int ROUNDS = NT_ / G;        // 16 (15 exchanges)
constexpr int NB     = 12;             // 12 bands x 4 rows
constexpr int NTHR   = NB * 64;        // 768 threads
constexpr int NBLK   = B_ * PIECES;    // 128 blocks
constexpr float DT2  = 1e-6f;          // DT*DT
constexpr float KLAP = 1e-8f;          // DT*DT/(DH*DH)
constexpr size_t FLAGS_BYTES = 4096;   // 128 blocks x 4 band-flags = 2 KB used
constexpr int RCAP = 6;
} // namespace

__device__ __forceinline__ float dpp_shr1(float v) {
    return __int_as_float(__builtin_amdgcn_update_dpp(
        0, __float_as_int(v), 0x138 /*WAVE_SHR1*/, 0xF, 0xF, true));
}
__device__ __forceinline__ float dpp_shl1(float v) {
    return __int_as_float(__builtin_amdgcn_update_dpp(
        0, __float_as_int(v), 0x130 /*WAVE_SHL1*/, 0xF, 0xF, true));
}

// Model (fit across R8/R13/R15): wall = 256 x max(VALU_burst, chain~560ns)
// + 15 x E, E ~= 6.4us. E is hop latency (barrier->drain->flag->MALL->poll->
// refill->barrier), not bytes. R19: keep R13's barrier steps + trapezoid
// EXACTLY; dissolve only the exchange:
//  - per-band flags: interior band 4+i publishes ITS 4-row slab (both levels),
//    wave-local vmcnt(0), sets flags[blk*4+i]. No block barrier needed -- the
//    flag covers only that wave's own stores.
//  - ghost band i polls flags[(blk-+1)*4+slot] (exact 1:1 source), refills,
//    wave-local drain. BOTH exchange block-barriers deleted; the next round's
//    step-1 __syncthreads is the only synchronizer.
//  - WAR on pub safe: last read of pub[par] is >=1 full step-barrier (plus the
//    flush barrier) before the step-1 rewrite (R13 parity argument).
// Data + math identical -> absmax bit-identical.
__device__ __forceinline__ void store_v4_sys(float* p, v4f v) {
    asm volatile("global_store_dwordx4 %0, %1, off sc0 sc1"
                 :: "v"(p), "v"(v) : "memory");
}
__device__ __forceinline__ v4f load_v4_sys(const float* p) {
    v4f r;
    asm volatile("global_load_dwordx4 %0, %1, off sc0 sc1"
                 : "=v"(r) : "v"(p) : "memory");
    return r;
}

extern "C" __global__
__attribute__((amdgpu_flat_work_group_size(NTHR, NTHR), amdgpu_waves_per_eu(4, 4)))
void wave_reg_kernel(const float* __restrict__ x,
                     const float* __restrict__ vp,
                     const int* __restrict__ src_loc,
                     const int* __restrict__ rec_loc,
                     float* __restrict__ out,
                     int* __restrict__ flags,   // [128][4] per-band round flags
                     float* __restrict__ gbuf)  // [par2][128][lvl2][16][256]
{
    __shared__ float pub[2][2][NB][256];   // 48 KB: [par][top/bot][band][col]
    __shared__ float wav[NT_];             // 1 KB wavelet
    __shared__ float recbuf[G][NREC_];     // 4 KB receiver staging (per round)
    __shared__ unsigned char recown[NREC_];// per-rec ownership of this block

    const int bid  = blockIdx.x;
    const int b    = bid & 7;
    const int p    = bid >> 3;             // 0..15
    const int blk  = b * PIECES + p;
    const int tid  = threadIdx.x;
    const int band = tid >> 6;             // wave id 0..11 -> 4 ext rows
    const int lane = tid & 63;
    const int c0   = lane << 2;            // first owned col (0..252)
    const int grt  = p * IROWS - G + (band << 2);  // global row of owned row 0

    // trapezoid cutoff (R13-proven): {3,7,11,15,16,16,16,16,15,11,7,3}
    const int cut = (band < 4) ? ((band << 2) + 3)
                  : ((band < 8) ? G : (47 - (band << 2)));

    if (tid < NT_) wav[tid] = x[b * NT_ + tid];
    if (tid < NREC_) {
        int rz = rec_loc[(b * NREC_ + tid) * 2 + 0];
        recown[tid] = (rz >= p * IROWS && rz < p * IROWS + IROWS) ? 1 : 0;
    }

    // cf = vp^2*DT^2/DH^2 masked; cf2 = 2 - 4*cf
    v4f cf[4], cf2[4];
#pragma unroll
    for (int i = 0; i < 4; ++i) {
        int gr = grt + i;
        int crow = gr < 0 ? 0 : (gr > 255 ? 255 : gr);
        bool rowok = (gr >= 1) && (gr <= 254);
        v4f vv = *(const v4f*)&vp[crow * NX_ + c0];
        float cc[4];
#pragma unroll
        for (int k = 0; k < 4; ++k) {
            int col = c0 + k;
            float vk = (k == 0) ? vv.x : (k == 1) ? vv.y : (k == 2) ? vv.z : vv.w;
            cc[k] = (rowok && col >= 1 && col <= 254) ? vk * vk * KLAP : 0.f;
        }
        cf[i].x = cc[0]; cf[i].y = cc[1]; cf[i].z = cc[2]; cf[i].w = cc[3];
        cf2[i].x = 2.f - 4.f * cc[0]; cf2[i].y = 2.f - 4.f * cc[1];
        cf2[i].z = 2.f - 4.f * cc[2]; cf2[i].w = 2.f - 4.f * cc[3];
    }

    // source ownership (ghost rows included: ghost evolution must replay it)
    const int sz = src_loc[b * 2 + 0], sx = src_loc[b * 2 + 1];
    const int si = sz - grt;
    const int sj = sx - c0;
    const bool has_src = ((unsigned)si < 4u) && ((unsigned)sj < 4u);
    const bool wave_has_src = __any(has_src);

    // receiver slots: interior owner only (unique writer). pk=(r<<4)|(i<<2)|j
    int rs[RCAP]; int rcnt = 0;
#pragma unroll 1
    for (int r = 0; r < NREC_; ++r) {
        int rz = rec_loc[(b * NREC_ + r) * 2 + 0];
        int rx = rec_loc[(b * NREC_ + r) * 2 + 1];
        int i = rz - grt, j = rx - c0;
        if (rz >= p * IROWS && rz < p * IROWS + IROWS &&
            (unsigned)i < 4u && (unsigned)j < 4u) {
            if (rcnt < RCAP) rs[rcnt] = (r << 4) | (i << 2) | j;
            ++rcnt;
        }
    }
    if (rcnt > RCAP) rcnt = RCAP;
    const bool wave_has_rec = __any(rcnt > 0);
    float* outb = out + (size_t)b * NT_ * NREC_;

    v4f A[4], Bv[4];
    {
        v4f z = {0.f, 0.f, 0.f, 0.f};
#pragma unroll
        for (int i = 0; i < 4; ++i) { A[i] = z; Bv[i] = z; }
    }

    // gbuf slab pointer: [par][blk][lvl][row][col]; interior = the slab.
    auto gptr = [&](int e, int bk, int lvl, int rr) -> float* {
        return gbuf + ((((size_t)(e & 1) * NBLK + bk) * 2 + lvl) * 16 + rr) * 256;
    };

    // one step: P <- update(C, P); P becomes current. par = t&1. (R13 exact)
    auto step = [&](v4f (&C)[4], v4f (&P)[4], int t, int par) {
        const int k = (t & (G - 1)) + 1;
        if (k <= cut + 1) {                 // publish window = compute window +1
            *(v4f*)&pub[par][0][band][c0] = C[0];  // top row (S halo of band-1)
            *(v4f*)&pub[par][1][band][c0] = C[3];  // bottom row (N halo of band+1)
        }
        __syncthreads();
        if (k > cut) return;                // all this band's rows are dead now
        v4f nn, ss;
        if (band > 0)      nn = *(const v4f*)&pub[par][1][band - 1][c0];
        else               { nn.x = 0.f; nn.y = 0.f; nn.z = 0.f; nn.w = 0.f; }
        if (band < NB - 1) ss = *(const v4f*)&pub[par][0][band + 1][c0];
        else               { ss.x = 0.f; ss.y = 0.f; ss.z = 0.f; ss.w = 0.f; }
#pragma unroll
        for (int i = 0; i < 4; ++i) {
            v4f n = (i == 0) ? nn : C[i - 1];
            v4f s = (i == 3) ? ss : C[i + 1];
            float wv = dpp_shr1(C[i].w);   // col c0-1 (lane0 -> 0: cf=0 masks)
            float ev = dpp_shl1(C[i].x);   // col c0+4 (lane63 -> 0: cf=0 masks)
            v4f hn;
            { float sm = (n.x + s.x) + (wv     + C[i].y);
              hn.x = fmaf(cf[i].x, sm, fmaf(cf2[i].x, C[i].x, -P[i].x)); }
            { float sm = (n.y + s.y) + (C[i].x + C[i].z);
              hn.y = fmaf(cf[i].y, sm, fmaf(cf2[i].y, C[i].y, -P[i].y)); }
            { float sm = (n.z + s.z) + (C[i].y + C[i].w);
              hn.z = fmaf(cf[i].z, sm, fmaf(cf2[i].z, C[i].z, -P[i].z)); }
            { float sm = (n.w + s.w) + (C[i].z + ev);
              hn.w = fmaf(cf[i].w, sm, fmaf(cf2[i].w, C[i].w, -P[i].w)); }
            P[i] = hn;
        }
        if (wave_has_src) {
            const float sv = DT2 * wav[t];
#pragma unroll
            for (int i = 0; i < 4; ++i) {
                if (has_src && si == i) {
                    if      (sj == 0) P[i].x += sv;
                    else if (sj == 1) P[i].y += sv;
                    else if (sj == 2) P[i].z += sv;
                    else              P[i].w += sv;
                }
            }
        }
        if (wave_has_rec) {
#pragma unroll
            for (int kk = 0; kk < RCAP; ++kk) {
                if (rcnt > kk) {
                    int pk = rs[kk];
                    int i = (pk >> 2) & 3, j = pk & 3, r = pk >> 4;
                    v4f t01 = (i & 1) ? P[1] : P[0];
                    v4f t23 = (i & 1) ? P[3] : P[2];
                    v4f rw  = (i & 2) ? t23 : t01;
                    float c01 = (j & 1) ? rw.y : rw.x;
                    float c23 = (j & 1) ? rw.w : rw.z;
                    recbuf[t & (G - 1)][r] = (j & 2) ? c23 : c01;
                }
            }
        }
        // no trailing barrier: next step uses pub[par^1] (parity double-buffer)
    };

    int t = 0;
#pragma unroll 1
    for (int e = 0; e < ROUNDS; ++e) {
#pragma unroll 1
        for (int s = 0; s < G; s += 2) {
            step(A, Bv, t, 0);      // t even: cur=A, par=0
            step(Bv, A, t + 1, 1);  // t odd:  cur=B, par=1
            t += 2;
        }
        // ---- barrier-free round boundary ----
        // interior band publishes ITS slab first (critical path front):
        // 8 sys-stores -> wave-local drain -> own flag. No block barrier.
        if (band >= 4 && band < 8 && e < ROUNDS - 1) {
            int rr0 = (band - 4) << 2;
#pragma unroll
            for (int i = 0; i < 4; ++i) {
                store_v4_sys(&gptr(e, blk, 0, rr0 + i)[c0], A[i]);
                store_v4_sys(&gptr(e, blk, 1, rr0 + i)[c0], Bv[i]);
            }
            asm volatile("s_waitcnt vmcnt(0)" ::: "memory");  // wave-local
            if (lane == 0)
                __hip_atomic_store(&flags[blk * 4 + (band - 4)], e + 1,
                                   __ATOMIC_RELAXED, __HIP_MEMORY_SCOPE_SYSTEM);
        }
        // flush this round's receiver samples (needs one LDS barrier)
        __syncthreads();
#pragma unroll 1
        for (int idx = tid; idx < G * NREC_; idx += NTHR) {
            int s = idx >> 6, r = idx & 63;
            if (recown[r]) outb[(e * G + s) * NREC_ + r] = recbuf[s][r];
        }
        // ghost bands: poll their one source-band flag, refill, wave-local
        // drain. Interior bands run ahead to next round's step-1 barrier.
        if (e < ROUNDS - 1) {
            if (band < 4 && p > 0) {           // top ghost <- blk-1 band 4+band
                if (lane == 0)
                    while (__hip_atomic_load(&flags[(blk - 1) * 4 + band],
                             __ATOMIC_RELAXED, __HIP_MEMORY_SCOPE_SYSTEM) < e + 1)
                        __builtin_amdgcn_s_sleep(1);
                int rr0 = band << 2;           // ext rows 0..15 == slab rows
#pragma unroll
                for (int i = 0; i < 4; ++i) {
                    A[i]  = load_v4_sys(&gptr(e, blk - 1, 0, rr0 + i)[c0]);
                    Bv[i] = load_v4_sys(&gptr(e, blk - 1, 1, rr0 + i)[c0]);
                }
                asm volatile("s_waitcnt vmcnt(0)" ::: "memory");  // rule #18
                __builtin_amdgcn_sched_barrier(0);
            }
            if (band >= 8 && p < PIECES - 1) { // bottom ghost <- blk+1 band-4
                if (lane == 0)
                    while (__hip_atomic_load(&flags[(blk + 1) * 4 + (band - 8)],
                             __ATOMIC_RELAXED, __HIP_MEMORY_SCOPE_SYSTEM) < e + 1)
                        __builtin_amdgcn_s_sleep(1);
                int rr0 = (band - 8) << 2;     // ext rows 32..47 == slab rows
#pragma unroll
                for (int i = 0; i < 4; ++i) {
                    A[i]  = load_v4_sys(&gptr(e, blk + 1, 0, rr0 + i)[c0]);
                    Bv[i] = load_v4_sys(&gptr(e, blk + 1, 1, rr0 + i)[c0]);
                }
                asm volatile("s_waitcnt vmcnt(0)" ::: "memory");  // rule #18
                __builtin_amdgcn_sched_barrier(0);
            }
        }
        // no trailing barrier: the next round's step-1 __syncthreads is the
        // synchronizer. WAR on pub: last read of pub[0] was step 15, >=1 full
        // step barrier + the flush barrier before the step-1 rewrite.
    }
}

extern "C" void kernel_launch(void* const* d_in, const int* in_sizes, int n_in,
                              void* d_out, int out_size, void* d_ws, size_t ws_size,
                              hipStream_t stream) {
    const float* x   = (const float*)d_in[0];
    const float* vp  = (const float*)d_in[1];
    const int*   src = (const int*)d_in[2];
    const int*   rec = (const int*)d_in[3];
    float*       o   = (float*)d_out;
    int*   flags = (int*)d_ws;
    float* gbuf  = (float*)((char*)d_ws + FLAGS_BYTES);
    (void)hipMemsetAsync(d_ws, 0, FLAGS_BYTES, stream);   // flags must start at 0
    hipLaunchKernelGGL(wave_reg_kernel, dim3(NBLK), dim3(NTHR), 0, stream,
                       x, vp, src, rec, o, flags, gbuf);
}